// Round 6
// baseline (473.306 us; speedup 1.0000x reference)
//
#include <hip/hip_runtime.h>
#include <hip/hip_bf16.h>

typedef _Float16 f16;
typedef f16 f16x4 __attribute__((ext_vector_type(4)));
typedef f16 f16x8 __attribute__((ext_vector_type(8)));
typedef __fp16 h16x2 __attribute__((ext_vector_type(2)));
typedef __fp16 h16x4 __attribute__((ext_vector_type(4)));
typedef float f32x4 __attribute__((ext_vector_type(4)));
typedef float f32x16 __attribute__((ext_vector_type(16)));

#define MT 64           // points per block; 8 waves; VGPR(~120) -> 2 blocks/CU = 16 waves/CU
#define LDST 260        // f16 LDS row stride: 520 B -> measured ZERO bank conflicts w/ 8B ops
#define INV2PI 0.15915494309189535f

// ---------------- prep: fragment-major Wt (layout unchanged from R0) ----------------
// wt layout: frag[(layer*8 + wcblk)*16 + kblk][lane][8]  (1 KB per frag, lane-major)
// A[i=lane&31][k = kblk*16 + (lane>>5)*8 + j] = wh[layer][k][wcblk*32 + (lane&31)]
__global__ __launch_bounds__(64)
void prep_wt(const float* __restrict__ wh, f16* __restrict__ wt) {
    const int b = blockIdx.x;                 // 512 = layer(4) x wcblk(8) x kblk(16)
    const int layer = b >> 7, wcblk = (b >> 4) & 7, kblk = b & 15;
    const int lane = threadIdx.x;
    const int l31 = lane & 31, lh = lane >> 5;
    const float* src = wh + layer * 65536 + (kblk * 16 + lh * 8) * 256 + wcblk * 32 + l31;
    f16x8 v;
#pragma unroll
    for (int j = 0; j < 8; j++) v[j] = (f16)src[j * 256];   // 128B-coalesced per half-wave
    *(f16x8*)(wt + b * 512 + lane * 8) = v;                  // 1KB coalesced store
}

// ---------------- fused SIREN ----------------
__device__ inline f16x8 lds_ld8(const f16* p) {
    // two 8B LDS loads (rows are 8B- but not 16B-aligned with LDST=260)
    f16x4 lo = *(const f16x4*)p;
    f16x4 hi = *(const f16x4*)(p + 4);
    return __builtin_shufflevector(lo, hi, 0, 1, 2, 3, 4, 5, 6, 7);
}

__device__ inline f16x4 pk4(float z0, float z1, float z2, float z3) {
    h16x2 a = __builtin_amdgcn_cvt_pkrtz(z0, z1);
    h16x2 b = __builtin_amdgcn_cvt_pkrtz(z2, z3);
    h16x4 r = __builtin_shufflevector(a, b, 0, 1, 2, 3);
    return __builtin_bit_cast(f16x4, r);
}

__global__ __launch_bounds__(512, 4)
void siren_fused(const float* __restrict__ coords,
                 const float* __restrict__ ow1, const float* __restrict__ ob1,
                 const float* __restrict__ ow2, const float* __restrict__ ob2,
                 const float* __restrict__ w0, const float* __restrict__ b0,
                 const f16* __restrict__ wt,    // fragment-major, see prep_wt
                 const float* __restrict__ bh,  // [4][256]
                 const float* __restrict__ wf,  // [256]
                 const float* __restrict__ bf,  // [1]
                 float* __restrict__ out) {
    __shared__ __align__(16) f16 Xs[MT * LDST];   // 33280 B activations (in-place per layer)
    __shared__ float om_rev[MT];                  // omega / (2*pi)
    __shared__ __align__(16) float crd[MT * 4];
    __shared__ __align__(16) float wf_s[256];

    const int t = threadIdx.x;
    const long base_pt = (long)blockIdx.x * MT;

    const int lane = t & 63;
    const int wave = t >> 6;          // 8 waves = 8 wcblks
    const int l31 = lane & 31;
    const int lh = lane >> 5;         // half-wave: k-offset 8
    const int wc0 = wave * 32;

    // ---- stage coords + wf ----
    if (t < MT) ((f32x4*)crd)[t] = ((const f32x4*)(coords + base_pt * 4))[t];
    if (t < 256) wf_s[t] = wf[t];
    __syncthreads();

    // ---- omega predictor: 8 threads/point, shfl-reduced ----
    {
        const int pt = t >> 3, q = t & 7;
        const float c0 = crd[pt * 4], c1 = crd[pt * 4 + 1], c2 = crd[pt * 4 + 2], c3 = crd[pt * 4 + 3];
        float z2p = 0.f;
#pragma unroll
        for (int jj = 0; jj < 8; jj++) {
            const int j = q * 8 + jj;
            float z = ob1[j] + c0 * ow1[j] + c1 * ow1[64 + j] + c2 * ow1[128 + j] + c3 * ow1[192 + j];
            z2p += fmaxf(z, 0.f) * ow2[j];
        }
        z2p += __shfl_xor(z2p, 1, 64);
        z2p += __shfl_xor(z2p, 2, 64);
        z2p += __shfl_xor(z2p, 4, 64);
        if (q == 0) {
            const float sig = 1.f / (1.f + __expf(-(z2p + ob2[0])));
            om_rev[pt] = (10.f + 90.f * sig) * INV2PI;
        }
    }

    // ---- preload layer-0 A (whole layer, 16 frags = 64 VGPR); latency hides
    //      under the omega-barrier + layer-0 sin phase ----
    f16x8 a[16];
    {
        const f16* af = wt + ((0 * 8 + wave) * 16) * 512 + lane * 8;
#pragma unroll
        for (int kb = 0; kb < 16; kb++) a[kb] = *(const f16x8*)(af + kb * 512);
    }
    __syncthreads();   // om_rev ready

    // ---- layer 0 (K=4, fp32 vector): Xs = sin(omega*(coords@w0+b0)) ----
    // 8 threads/point, chunk-interleaved: thread q handles chunks q, q+8 (16 ch each)
    {
        const int pt = t >> 3, q = t & 7;
        const float c0 = crd[pt * 4], c1 = crd[pt * 4 + 1], c2 = crd[pt * 4 + 2], c3 = crd[pt * 4 + 3];
        const float orv = om_rev[pt];
#pragma unroll
        for (int i = 0; i < 2; i++) {
            const int ch0 = (q + 8 * i) * 16;
#pragma unroll
            for (int c = 0; c < 16; c += 4) {
                const int ch = ch0 + c;
                f32x4 wv0 = *(const f32x4*)(w0 + 0 * 256 + ch);
                f32x4 wv1 = *(const f32x4*)(w0 + 1 * 256 + ch);
                f32x4 wv2 = *(const f32x4*)(w0 + 2 * 256 + ch);
                f32x4 wv3 = *(const f32x4*)(w0 + 3 * 256 + ch);
                f32x4 bv  = *(const f32x4*)(b0 + ch);
                float z[4];
#pragma unroll
                for (int j = 0; j < 4; j++) {
                    float zz = bv[j] + c0 * wv0[j] + c1 * wv1[j] + c2 * wv2[j] + c3 * wv3[j];
                    z[j] = __builtin_amdgcn_sinf(orv * zz);
                }
                *(f16x4*)&Xs[pt * LDST + ch] = pk4(z[0], z[1], z[2], z[3]);
            }
        }
    }
    __syncthreads();

    // ---- hidden layers: Z^T = Wt (A) x X (B), 32x32x16 f16 MFMA ----
    // Wave tile: 32 cols (own wcblk) x 64 rows (rt=2). A fully register-resident per
    // layer -> inner loop is PURE {4 ds_read_b64 + 2 MFMA}: no global ops, no ring.
    // Next layer's A refills right after the kb loop, hidden under the sin epilogue.
#pragma unroll 1
    for (int layer = 0; layer < 4; layer++) {
        f32x16 acc[2];
#pragma unroll
        for (int g = 0; g < 4; g++) {
            // acc init = bias (D row = channel): ch = wc0 + g*8 + lh*4 + j
            f32x4 bb = *(const f32x4*)(bh + layer * 256 + wc0 + g * 8 + lh * 4);
#pragma unroll
            for (int j = 0; j < 4; j++) {
                acc[0][g * 4 + j] = bb[j];
                acc[1][g * 4 + j] = bb[j];
            }
        }

        const f16* bptr = &Xs[l31 * LDST + lh * 8];   // B: lane row = prow, k = kb*16+lh*8+j

#pragma unroll
        for (int kb = 0; kb < 16; kb++) {
            f16x8 bv0 = lds_ld8(bptr + 0 * 32 * LDST + kb * 16);
            f16x8 bv1 = lds_ld8(bptr + 1 * 32 * LDST + kb * 16);
            acc[0] = __builtin_amdgcn_mfma_f32_32x32x16_f16(a[kb], bv0, acc[0], 0, 0, 0);
            acc[1] = __builtin_amdgcn_mfma_f32_32x32x16_f16(a[kb], bv1, acc[1], 0, 0, 0);
        }

        if (layer < 3) {   // refill A for next layer; L2 latency hides under epilogue sins
            const f16* af = wt + (((layer + 1) * 8 + wave) * 16) * 512 + lane * 8;
#pragma unroll
            for (int kb = 0; kb < 16; kb++) a[kb] = *(const f16x8*)(af + kb * 512);
        }
        __syncthreads();   // all Xs reads done

        // epilogue: x = sin(om*acc), write f16 back to Xs in place
        const float orv0 = om_rev[l31];
        const float orv1 = om_rev[32 + l31];
#pragma unroll
        for (int g = 0; g < 4; g++) {
            const int wc = wc0 + g * 8 + lh * 4;   // D row = (reg&3)+8*(reg>>2)+4*lh
            float z[4];
#pragma unroll
            for (int j = 0; j < 4; j++) z[j] = __builtin_amdgcn_sinf(orv0 * acc[0][g * 4 + j]);
            *(f16x4*)&Xs[(0 * 32 + l31) * LDST + wc] = pk4(z[0], z[1], z[2], z[3]);
#pragma unroll
            for (int j = 0; j < 4; j++) z[j] = __builtin_amdgcn_sinf(orv1 * acc[1][g * 4 + j]);
            *(f16x4*)&Xs[(1 * 32 + l31) * LDST + wc] = pk4(z[0], z[1], z[2], z[3]);
        }
        __syncthreads();
    }

    // ---- final layer: out = X @ wf + bf (fp32 vector), chunk-interleaved ----
    {
        const int pt = t >> 3, q = t & 7;
        const f16* xrow = &Xs[pt * LDST];
        float s = 0.f;
#pragma unroll
        for (int i = 0; i < 2; i++) {
            const int ch0 = (q + 8 * i) * 16;
#pragma unroll
            for (int c = 0; c < 16; c += 4) {
                f16x4 xv = *(const f16x4*)(xrow + ch0 + c);
                f32x4 wv = *(const f32x4*)&wf_s[ch0 + c];
                s += (float)xv[0] * wv[0] + (float)xv[1] * wv[1]
                   + (float)xv[2] * wv[2] + (float)xv[3] * wv[3];
            }
        }
        s += __shfl_xor(s, 1, 64);
        s += __shfl_xor(s, 2, 64);
        s += __shfl_xor(s, 4, 64);
        if (q == 0) out[base_pt + pt] = s + bf[0];
    }
}

extern "C" void kernel_launch(void* const* d_in, const int* in_sizes, int n_in,
                              void* d_out, int out_size, void* d_ws, size_t ws_size,
                              hipStream_t stream) {
    (void)in_sizes; (void)n_in; (void)out_size; (void)ws_size;
    const float* coords = (const float*)d_in[0];
    const float* ow1 = (const float*)d_in[1];
    const float* ob1 = (const float*)d_in[2];
    const float* ow2 = (const float*)d_in[3];
    const float* ob2 = (const float*)d_in[4];
    const float* w0  = (const float*)d_in[5];
    const float* b0  = (const float*)d_in[6];
    const float* wh  = (const float*)d_in[7];
    const float* bh  = (const float*)d_in[8];
    const float* wf  = (const float*)d_in[9];
    const float* bf  = (const float*)d_in[10];
    float* out = (float*)d_out;
    f16* wt = (f16*)d_ws;   // 512 frags * 1KB = 512 KB

    prep_wt<<<512, 64, 0, stream>>>(wh, wt);
    siren_fused<<<524288 / MT, 512, 0, stream>>>(coords, ow1, ob1, ow2, ob2,
                                                 w0, b0, wt, bh, wf, bf, out);
}